// Round 1
// baseline (606.000 us; speedup 1.0000x reference)
//
#include <hip/hip_runtime.h>

typedef float floatx4 __attribute__((ext_vector_type(4)));
typedef short shortx8 __attribute__((ext_vector_type(8)));

#define E_DIM 1024
#define F_DIM 4096
#define BATCH 4
#define SEQ 1024
#define NH 16
#define HD 64
#define MROWS (BATCH*SEQ)   // 4096

__device__ __forceinline__ unsigned short f2bf(float f) {
    union { float f; unsigned u; } un; un.f = f;
    unsigned u = un.u;
    u += 0x7fffu + ((u >> 16) & 1u);   // RNE
    return (unsigned short)(u >> 16);
}

// ---------------- fp32 -> bf16 convert (weights) ----------------
__global__ void f2b_kernel(const float* __restrict__ in, unsigned short* __restrict__ out, int n) {
    int i = blockIdx.x * 256 + threadIdx.x;
    if (i < n) out[i] = f2bf(in[i]);
}

// ---------------- LayerNorm (row=1024), fp32 in, bf16 out ----------------
__global__ __launch_bounds__(256) void ln_kernel(const float* __restrict__ x,
                                                 const float* __restrict__ w,
                                                 const float* __restrict__ b,
                                                 unsigned short* __restrict__ out) {
    int row = blockIdx.x;
    const float* xr = x + (size_t)row * E_DIM;
    float v[4];
    float s = 0.f, ss = 0.f;
    for (int i = 0; i < 4; ++i) {
        v[i] = xr[threadIdx.x + i * 256];
        s += v[i]; ss += v[i] * v[i];
    }
    for (int m = 32; m; m >>= 1) { s += __shfl_xor(s, m); ss += __shfl_xor(ss, m); }
    __shared__ float red[8];
    int wave = threadIdx.x >> 6;
    if ((threadIdx.x & 63) == 0) { red[wave] = s; red[wave + 4] = ss; }
    __syncthreads();
    s = red[0] + red[1] + red[2] + red[3];
    ss = red[4] + red[5] + red[6] + red[7];
    float mu = s * (1.0f / E_DIM);
    float var = ss * (1.0f / E_DIM) - mu * mu;
    float rs = rsqrtf(var + 1e-5f);
    for (int i = 0; i < 4; ++i) {
        int c = threadIdx.x + i * 256;
        out[(size_t)row * E_DIM + c] = f2bf((v[i] - mu) * rs * w[c] + b[c]);
    }
}

// ---------------- GEMM: C[M,N] = A[M,K] @ B[N,K]^T + bias, epilogues ----------------
// EPI bits: 1=gelu, 2=residual(fp32), 4=store fp32, 8=store bf16, 16=qkv scatter
#define TM 128
#define TN 128
#define TKK 64
#define LDK 72   // 64 + 8 pad, keeps 16B alignment of rows, 2-way-free banks

template<int EPI>
__global__ __launch_bounds__(256, 2) void gemm_bt(
        const unsigned short* __restrict__ A, const unsigned short* __restrict__ Bw,
        const float* __restrict__ bias, const float* __restrict__ resid,
        float* __restrict__ Cf, unsigned short* __restrict__ Cb,
        unsigned short* __restrict__ qp, unsigned short* __restrict__ kp,
        unsigned short* __restrict__ vp, int M, int N, int K) {
    __shared__ unsigned short sA[TM * LDK];
    __shared__ unsigned short sB[TN * LDK];
    int tid = threadIdx.x;
    int n0 = blockIdx.x * TN, m0 = blockIdx.y * TM;
    int wave = tid >> 6, lane = tid & 63;
    int wm = (wave & 1) * 64, wn = (wave >> 1) * 64;
    int l15 = lane & 15, quad = lane >> 4;

    floatx4 acc[4][4];
    for (int i = 0; i < 4; ++i) for (int j = 0; j < 4; ++j) acc[i][j] = (floatx4)0.f;

    for (int k0 = 0; k0 < K; k0 += TKK) {
        __syncthreads();
        for (int p = 0; p < 4; ++p) {
            int idx = p * 2048 + tid * 8;
            int r = idx >> 6, c = idx & 63;
            *(shortx8*)&sA[r * LDK + c] = *(const shortx8*)&A[(size_t)(m0 + r) * K + k0 + c];
            *(shortx8*)&sB[r * LDK + c] = *(const shortx8*)&Bw[(size_t)(n0 + r) * K + k0 + c];
        }
        __syncthreads();
        for (int kk = 0; kk < TKK; kk += 32) {
            shortx8 af[4], bfr[4];
            for (int i = 0; i < 4; ++i)
                af[i] = *(const shortx8*)&sA[(wm + i * 16 + l15) * LDK + kk + quad * 8];
            for (int j = 0; j < 4; ++j)
                bfr[j] = *(const shortx8*)&sB[(wn + j * 16 + l15) * LDK + kk + quad * 8];
            for (int i = 0; i < 4; ++i)
                for (int j = 0; j < 4; ++j)
                    acc[i][j] = __builtin_amdgcn_mfma_f32_16x16x32_bf16(af[i], bfr[j], acc[i][j], 0, 0, 0);
        }
    }

    for (int i = 0; i < 4; ++i) {
        int row = m0 + wm + i * 16 + quad * 4;
        for (int j = 0; j < 4; ++j) {
            int col = n0 + wn + j * 16 + l15;
            float bs = bias[col];
            for (int r = 0; r < 4; ++r) {
                float v = acc[i][j][r] + bs;
                int rr = row + r;
                if (EPI & 1) v = 0.5f * v * (1.0f + erff(v * 0.70710678f));
                if (EPI & 2) v += resid[(size_t)rr * N + col];
                if (EPI & 4) Cf[(size_t)rr * N + col] = v;
                if (EPI & 8) Cb[(size_t)rr * N + col] = f2bf(v);
                if (EPI & 16) {
                    int sel = col >> 10, hh = (col >> 6) & 15, d = col & 63;
                    int b = rr >> 10, t = rr & 1023;
                    unsigned short* dst = (sel == 0) ? qp : ((sel == 1) ? kp : vp);
                    dst[(((size_t)(b * NH + hh) * SEQ + t) << 6) + d] = f2bf(v);
                }
            }
        }
    }
}

// ---------------- Flash attention: causal, per-(b,h), q-tile 64/block ----------------
#define AKD 72   // K tile row stride (64+8)
#define AVS 40   // Vt / P row stride (32+8)

__global__ __launch_bounds__(256, 2) void attn_kernel(
        const unsigned short* __restrict__ q, const unsigned short* __restrict__ k,
        const unsigned short* __restrict__ v, unsigned short* __restrict__ out) {
    __shared__ unsigned short kt[32 * AKD];
    __shared__ unsigned short vt[64 * AVS];
    __shared__ unsigned short ps[4][16 * AVS];
    int tid = threadIdx.x;
    int wave = tid >> 6, lane = tid & 63, l15 = lane & 15, quad = lane >> 4;
    int bh = blockIdx.y;
    int q0 = blockIdx.x * 64;
    int qrow = q0 + wave * 16;
    const unsigned short* qp = q + (size_t)bh * SEQ * HD;
    const unsigned short* kp = k + (size_t)bh * SEQ * HD;
    const unsigned short* vp = v + (size_t)bh * SEQ * HD;

    shortx8 qa0 = *(const shortx8*)&qp[(size_t)(qrow + l15) * HD + quad * 8];
    shortx8 qa1 = *(const shortx8*)&qp[(size_t)(qrow + l15) * HD + 32 + quad * 8];

    floatx4 o[4];
    for (int d = 0; d < 4; ++d) o[d] = (floatx4)0.f;
    float mrun[4], lrun[4];
    for (int r = 0; r < 4; ++r) { mrun[r] = -1e30f; lrun[r] = 0.f; }

    int ntile = (q0 + 64) / 32;
    for (int t = 0; t < ntile; ++t) {
        int s0 = t * 32;
        __syncthreads();
        {
            int idx = tid * 8;
            int sr = idx >> 6, d0 = idx & 63;
            shortx8 k8 = *(const shortx8*)&kp[(size_t)(s0 + sr) * HD + d0];
            *(shortx8*)&kt[sr * AKD + d0] = k8;
            shortx8 v8 = *(const shortx8*)&vp[(size_t)(s0 + sr) * HD + d0];
            for (int j = 0; j < 8; ++j) vt[(d0 + j) * AVS + sr] = (unsigned short)v8[j];
        }
        __syncthreads();

        floatx4 sfr[2];
        sfr[0] = (floatx4)0.f; sfr[1] = (floatx4)0.f;
        for (int sub = 0; sub < 2; ++sub) {
            shortx8 kb0 = *(const shortx8*)&kt[(sub * 16 + l15) * AKD + quad * 8];
            shortx8 kb1 = *(const shortx8*)&kt[(sub * 16 + l15) * AKD + 32 + quad * 8];
            sfr[sub] = __builtin_amdgcn_mfma_f32_16x16x32_bf16(qa0, kb0, sfr[sub], 0, 0, 0);
            sfr[sub] = __builtin_amdgcn_mfma_f32_16x16x32_bf16(qa1, kb1, sfr[sub], 0, 0, 0);
        }
        const float scale = 0.125f * 1.44269504f;  // 1/sqrt(64) * log2(e)
        float pv0[4], pv1[4];
        for (int r = 0; r < 4; ++r) {
            int qg = qrow + quad * 4 + r;
            float v0 = sfr[0][r] * scale; if (s0 + l15 > qg) v0 = -1e30f;
            float v1 = sfr[1][r] * scale; if (s0 + 16 + l15 > qg) v1 = -1e30f;
            float mx = fmaxf(v0, v1);
            for (int mm = 8; mm; mm >>= 1) mx = fmaxf(mx, __shfl_xor(mx, mm));
            float mnew = fmaxf(mrun[r], mx);
            float alpha = exp2f(mrun[r] - mnew);
            float p0 = exp2f(v0 - mnew), p1 = exp2f(v1 - mnew);
            float sum = p0 + p1;
            for (int mm = 8; mm; mm >>= 1) sum += __shfl_xor(sum, mm);
            lrun[r] = lrun[r] * alpha + sum;
            mrun[r] = mnew;
            for (int d = 0; d < 4; ++d) o[d][r] = o[d][r] * alpha;
            pv0[r] = p0; pv1[r] = p1;
        }
        for (int r = 0; r < 4; ++r) {
            ps[wave][(quad * 4 + r) * AVS + l15] = f2bf(pv0[r]);
            ps[wave][(quad * 4 + r) * AVS + 16 + l15] = f2bf(pv1[r]);
        }
        __syncthreads();
        shortx8 pa = *(const shortx8*)&ps[wave][l15 * AVS + quad * 8];
        for (int d = 0; d < 4; ++d) {
            shortx8 vb = *(const shortx8*)&vt[(d * 16 + l15) * AVS + quad * 8];
            o[d] = __builtin_amdgcn_mfma_f32_16x16x32_bf16(pa, vb, o[d], 0, 0, 0);
        }
    }

    int b = bh >> 4, h = bh & 15;
    for (int r = 0; r < 4; ++r) {
        float inv = 1.0f / lrun[r];
        int m = (b << 10) + qrow + quad * 4 + r;
        for (int d = 0; d < 4; ++d)
            out[(size_t)m * E_DIM + h * HD + d * 16 + l15] = f2bf(o[d][r] * inv);
    }
}

// ---------------- launch ----------------
extern "C" void kernel_launch(void* const* d_in, const int* in_sizes, int n_in,
                              void* d_out, int out_size, void* d_ws, size_t ws_size,
                              hipStream_t stream) {
    const float* x     = (const float*)d_in[0];
    const float* ln1_w = (const float*)d_in[1];
    const float* ln1_b = (const float*)d_in[2];
    const float* ln2_w = (const float*)d_in[3];
    const float* ln2_b = (const float*)d_in[4];
    const float* qkv_w = (const float*)d_in[5];
    const float* qkv_b = (const float*)d_in[6];
    const float* out_w = (const float*)d_in[7];
    const float* out_b = (const float*)d_in[8];
    const float* fc1_w = (const float*)d_in[9];
    const float* fc1_b = (const float*)d_in[10];
    const float* fc2_w = (const float*)d_in[11];
    const float* fc2_b = (const float*)d_in[12];

    char* ws = (char*)d_ws;
    size_t off = 0;
    auto alloc = [&](size_t bytes) { char* p = ws + off; off += bytes; return p; };
    unsigned short* wq   = (unsigned short*)alloc((size_t)3 * E_DIM * E_DIM * 2);
    unsigned short* wo   = (unsigned short*)alloc((size_t)E_DIM * E_DIM * 2);
    unsigned short* w1   = (unsigned short*)alloc((size_t)F_DIM * E_DIM * 2);
    unsigned short* w2   = (unsigned short*)alloc((size_t)E_DIM * F_DIM * 2);
    unsigned short* h1   = (unsigned short*)alloc((size_t)MROWS * E_DIM * 2);
    unsigned short* qb   = (unsigned short*)alloc((size_t)MROWS * E_DIM * 2);
    unsigned short* kb   = (unsigned short*)alloc((size_t)MROWS * E_DIM * 2);
    unsigned short* vb   = (unsigned short*)alloc((size_t)MROWS * E_DIM * 2);
    unsigned short* attn = (unsigned short*)alloc((size_t)MROWS * E_DIM * 2);
    float*          x1   = (float*)alloc((size_t)MROWS * E_DIM * 4);
    unsigned short* h2   = (unsigned short*)alloc((size_t)MROWS * E_DIM * 2);
    unsigned short* g    = (unsigned short*)alloc((size_t)MROWS * F_DIM * 2);

    // weight conversion
    {
        int n;
        n = 3 * E_DIM * E_DIM; f2b_kernel<<<(n + 255) / 256, 256, 0, stream>>>(qkv_w, wq, n);
        n = E_DIM * E_DIM;     f2b_kernel<<<(n + 255) / 256, 256, 0, stream>>>(out_w, wo, n);
        n = F_DIM * E_DIM;     f2b_kernel<<<(n + 255) / 256, 256, 0, stream>>>(fc1_w, w1, n);
        n = E_DIM * F_DIM;     f2b_kernel<<<(n + 255) / 256, 256, 0, stream>>>(fc2_w, w2, n);
    }

    // LN1
    ln_kernel<<<MROWS, 256, 0, stream>>>(x, ln1_w, ln1_b, h1);
    // QKV gemm: [4096,3072] = h1 @ qkv_w^T, scatter to q/k/v [B,H,T,D]
    gemm_bt<16><<<dim3(3 * E_DIM / TN, MROWS / TM), 256, 0, stream>>>(
        h1, wq, qkv_b, nullptr, nullptr, nullptr, qb, kb, vb, MROWS, 3 * E_DIM, E_DIM);
    // attention
    attn_kernel<<<dim3(SEQ / 64, BATCH * NH), 256, 0, stream>>>(qb, kb, vb, attn);
    // out proj + residual(x) -> x1 fp32
    gemm_bt<2 | 4><<<dim3(E_DIM / TN, MROWS / TM), 256, 0, stream>>>(
        attn, wo, out_b, x, x1, nullptr, nullptr, nullptr, nullptr, MROWS, E_DIM, E_DIM);
    // LN2
    ln_kernel<<<MROWS, 256, 0, stream>>>(x1, ln2_w, ln2_b, h2);
    // FC1 + gelu -> g bf16
    gemm_bt<1 | 8><<<dim3(F_DIM / TN, MROWS / TM), 256, 0, stream>>>(
        h2, w1, fc1_b, nullptr, nullptr, g, nullptr, nullptr, nullptr, MROWS, F_DIM, E_DIM);
    // FC2 + residual(x1) -> d_out fp32
    gemm_bt<2 | 4><<<dim3(E_DIM / TN, MROWS / TM), 256, 0, stream>>>(
        g, w2, fc2_b, x1, (float*)d_out, nullptr, nullptr, nullptr, nullptr, MROWS, E_DIM, F_DIM);
}

// Round 2
// 461.445 us; speedup vs baseline: 1.3133x; 1.3133x over previous
//
#include <hip/hip_runtime.h>

typedef float floatx4 __attribute__((ext_vector_type(4)));
typedef short shortx8 __attribute__((ext_vector_type(8)));

#define E_DIM 1024
#define F_DIM 4096
#define BATCH 4
#define SEQ 1024
#define NH 16
#define HD 64
#define MROWS (BATCH*SEQ)   // 4096
#define QKV_N (3*E_DIM)     // 3072

typedef const __attribute__((address_space(1))) unsigned int* gas_ptr;
typedef __attribute__((address_space(3))) unsigned int* las_ptr;

__device__ __forceinline__ unsigned short f2bf(float f) {
    union { float f; unsigned u; } un; un.f = f;
    unsigned u = un.u;
    u += 0x7fffu + ((u >> 16) & 1u);   // RNE
    return (unsigned short)(u >> 16);
}

// ---------------- fp32 -> bf16 convert (weights) ----------------
__global__ void f2b_kernel(const float* __restrict__ in, unsigned short* __restrict__ out, int n) {
    int i = blockIdx.x * 256 + threadIdx.x;
    if (i < n) out[i] = f2bf(in[i]);
}

// ---------------- LayerNorm (row=1024), fp32 in, bf16 out ----------------
__global__ __launch_bounds__(256) void ln_kernel(const float* __restrict__ x,
                                                 const float* __restrict__ w,
                                                 const float* __restrict__ b,
                                                 unsigned short* __restrict__ out) {
    int row = blockIdx.x;
    const float* xr = x + (size_t)row * E_DIM;
    float v[4];
    float s = 0.f, ss = 0.f;
    for (int i = 0; i < 4; ++i) {
        v[i] = xr[threadIdx.x + i * 256];
        s += v[i]; ss += v[i] * v[i];
    }
    for (int m = 32; m; m >>= 1) { s += __shfl_xor(s, m); ss += __shfl_xor(ss, m); }
    __shared__ float red[8];
    int wave = threadIdx.x >> 6;
    if ((threadIdx.x & 63) == 0) { red[wave] = s; red[wave + 4] = ss; }
    __syncthreads();
    s = red[0] + red[1] + red[2] + red[3];
    ss = red[4] + red[5] + red[6] + red[7];
    float mu = s * (1.0f / E_DIM);
    float var = ss * (1.0f / E_DIM) - mu * mu;
    float rs = rsqrtf(var + 1e-5f);
    for (int i = 0; i < 4; ++i) {
        int c = threadIdx.x + i * 256;
        out[(size_t)row * E_DIM + c] = f2bf((v[i] - mu) * rs * w[c] + b[c]);
    }
}

// ---------------- GEMM: C[M,N] = A[M,K] @ B[N,K]^T + bias, epilogues ----------------
// m97 structure: 128x128 tile, BK=64, global_load_lds width-16 staging,
// XOR-swizzled LDS layout (swizzle folded into the GLOBAL address so the
// lane-contiguous LDS dest stays legal): 16B slot (r, sc) holds logical
// col-group cg = sc ^ (r&7). ds_read_b128 fragment reads then spread each
// quad across all 32 banks (2-way = free) instead of 16-way conflicts.
// EPI bits: 1=gelu, 2=residual(fp32 in), 4=store fp32, 8=store bf16
#define TM 128
#define TN 128
#define BK 64

template<int EPI>
__global__ __launch_bounds__(256) void gemm_bt(
        const unsigned short* __restrict__ A, const unsigned short* __restrict__ Bw,
        const float* __restrict__ bias, const float* __restrict__ resid,
        float* __restrict__ Cf, unsigned short* __restrict__ Cb,
        int M, int N, int K) {
    __shared__ unsigned short sA[TM * BK];
    __shared__ unsigned short sB[TN * BK];
    int tid = threadIdx.x;
    int wave = tid >> 6, lane = tid & 63;
    int n0 = blockIdx.x * TN, m0 = blockIdx.y * TM;
    int wm = (wave & 1) * 64, wn = (wave >> 1) * 64;
    int l15 = lane & 15, quad = lane >> 4;

    // staging: wave stages rows [wave*32, wave*32+32) in 4 insts of 8 rows.
    // lane l, inst p: row = wave*32 + p*8 + (l>>3); lds slot sc = l&7;
    // global col-group cg = sc ^ (row&7)  (the swizzle).
    int srow = wave * 32 + (lane >> 3);
    int scg  = (lane & 7) ^ (srow & 7);
    const unsigned short* Ag = A  + (size_t)(m0 + srow) * K + scg * 8;
    const unsigned short* Bg = Bw + (size_t)(n0 + srow) * K + scg * 8;

    floatx4 acc[4][4];
#pragma unroll
    for (int i = 0; i < 4; ++i)
#pragma unroll
        for (int j = 0; j < 4; ++j) acc[i][j] = (floatx4)0.f;

    for (int k0 = 0; k0 < K; k0 += BK) {
        __syncthreads();
#pragma unroll
        for (int p = 0; p < 4; ++p) {
            __builtin_amdgcn_global_load_lds((gas_ptr)(Ag + k0 + p * 8 * K),
                (las_ptr)&sA[(wave * 32 + p * 8) * BK], 16, 0, 0);
            __builtin_amdgcn_global_load_lds((gas_ptr)(Bg + k0 + p * 8 * K),
                (las_ptr)&sB[(wave * 32 + p * 8) * BK], 16, 0, 0);
        }
        __syncthreads();
#pragma unroll
        for (int kk8 = 0; kk8 < 8; kk8 += 4) {   // col-group base: kk = kk8*8
            shortx8 af[4], bfr[4];
#pragma unroll
            for (int i = 0; i < 4; ++i) {
                int R = wm + i * 16 + l15;
                int sc = (quad + kk8) ^ (R & 7);
                af[i] = *(const shortx8*)&sA[(R * 8 + sc) * 8];
            }
#pragma unroll
            for (int j = 0; j < 4; ++j) {
                int R = wn + j * 16 + l15;
                int sc = (quad + kk8) ^ (R & 7);
                bfr[j] = *(const shortx8*)&sB[(R * 8 + sc) * 8];
            }
#pragma unroll
            for (int i = 0; i < 4; ++i)
#pragma unroll
                for (int j = 0; j < 4; ++j)
                    acc[i][j] = __builtin_amdgcn_mfma_f32_16x16x32_bf16(af[i], bfr[j], acc[i][j], 0, 0, 0);
        }
    }

#pragma unroll
    for (int i = 0; i < 4; ++i) {
        int row = m0 + wm + i * 16 + quad * 4;
#pragma unroll
        for (int j = 0; j < 4; ++j) {
            int col = n0 + wn + j * 16 + l15;
            float bs = bias[col];
#pragma unroll
            for (int r = 0; r < 4; ++r) {
                float v = acc[i][j][r] + bs;
                int rr = row + r;
                if (EPI & 1) v = 0.5f * v * (1.0f + erff(v * 0.70710678f));
                if (EPI & 2) v += resid[(size_t)rr * N + col];
                if (EPI & 4) Cf[(size_t)rr * N + col] = v;
                if (EPI & 8) Cb[(size_t)rr * N + col] = f2bf(v);
            }
        }
    }
}

// ---------------- Flash attention: causal, reads strided QKV [M,3E] ----------------
#define AKD 72   // K tile row stride (64+8)
#define AVS 40   // Vt / P row stride (32+8)

__global__ __launch_bounds__(256, 2) void attn_kernel(
        const unsigned short* __restrict__ qkv, unsigned short* __restrict__ out) {
    __shared__ unsigned short kt[32 * AKD];
    __shared__ unsigned short vt[64 * AVS];
    __shared__ unsigned short ps[4][16 * AVS];
    int tid = threadIdx.x;
    int wave = tid >> 6, lane = tid & 63, l15 = lane & 15, quad = lane >> 4;
    int bh = blockIdx.y;
    int b = bh >> 4, h = bh & 15;
    int q0 = blockIdx.x * 64;
    int qrow = q0 + wave * 16;
    // q/k/v rows for (b,h,t): qkv[(b*SEQ+t)*3E + sel*E + h*64 + d]
    const unsigned short* qp = qkv + (size_t)b * SEQ * QKV_N + h * HD;
    const unsigned short* kp = qp + E_DIM;
    const unsigned short* vp = qp + 2 * E_DIM;

    shortx8 qa0 = *(const shortx8*)&qp[(size_t)(qrow + l15) * QKV_N + quad * 8];
    shortx8 qa1 = *(const shortx8*)&qp[(size_t)(qrow + l15) * QKV_N + 32 + quad * 8];

    floatx4 o[4];
    for (int d = 0; d < 4; ++d) o[d] = (floatx4)0.f;
    float mrun[4], lrun[4];
    for (int r = 0; r < 4; ++r) { mrun[r] = -1e30f; lrun[r] = 0.f; }

    int ntile = (q0 + 64) / 32;
    for (int t = 0; t < ntile; ++t) {
        int s0 = t * 32;
        __syncthreads();
        {
            int idx = tid * 8;
            int sr = idx >> 6, d0 = idx & 63;
            shortx8 k8 = *(const shortx8*)&kp[(size_t)(s0 + sr) * QKV_N + d0];
            *(shortx8*)&kt[sr * AKD + d0] = k8;
            shortx8 v8 = *(const shortx8*)&vp[(size_t)(s0 + sr) * QKV_N + d0];
            for (int j = 0; j < 8; ++j) vt[(d0 + j) * AVS + sr] = (unsigned short)v8[j];
        }
        __syncthreads();

        floatx4 sfr[2];
        sfr[0] = (floatx4)0.f; sfr[1] = (floatx4)0.f;
        for (int sub = 0; sub < 2; ++sub) {
            shortx8 kb0 = *(const shortx8*)&kt[(sub * 16 + l15) * AKD + quad * 8];
            shortx8 kb1 = *(const shortx8*)&kt[(sub * 16 + l15) * AKD + 32 + quad * 8];
            sfr[sub] = __builtin_amdgcn_mfma_f32_16x16x32_bf16(qa0, kb0, sfr[sub], 0, 0, 0);
            sfr[sub] = __builtin_amdgcn_mfma_f32_16x16x32_bf16(qa1, kb1, sfr[sub], 0, 0, 0);
        }
        const float scale = 0.125f * 1.44269504f;  // 1/sqrt(64) * log2(e)
        float pv0[4], pv1[4];
        for (int r = 0; r < 4; ++r) {
            int qg = qrow + quad * 4 + r;
            float v0 = sfr[0][r] * scale; if (s0 + l15 > qg) v0 = -1e30f;
            float v1 = sfr[1][r] * scale; if (s0 + 16 + l15 > qg) v1 = -1e30f;
            float mx = fmaxf(v0, v1);
            for (int mm = 8; mm; mm >>= 1) mx = fmaxf(mx, __shfl_xor(mx, mm));
            float mnew = fmaxf(mrun[r], mx);
            float alpha = exp2f(mrun[r] - mnew);
            float p0 = exp2f(v0 - mnew), p1 = exp2f(v1 - mnew);
            float sum = p0 + p1;
            for (int mm = 8; mm; mm >>= 1) sum += __shfl_xor(sum, mm);
            lrun[r] = lrun[r] * alpha + sum;
            mrun[r] = mnew;
            for (int d = 0; d < 4; ++d) o[d][r] = o[d][r] * alpha;
            pv0[r] = p0; pv1[r] = p1;
        }
        for (int r = 0; r < 4; ++r) {
            ps[wave][(quad * 4 + r) * AVS + l15] = f2bf(pv0[r]);
            ps[wave][(quad * 4 + r) * AVS + 16 + l15] = f2bf(pv1[r]);
        }
        __syncthreads();
        shortx8 pa = *(const shortx8*)&ps[wave][l15 * AVS + quad * 8];
        for (int d = 0; d < 4; ++d) {
            shortx8 vb = *(const shortx8*)&vt[(d * 16 + l15) * AVS + quad * 8];
            o[d] = __builtin_amdgcn_mfma_f32_16x16x32_bf16(pa, vb, o[d], 0, 0, 0);
        }
    }

    for (int r = 0; r < 4; ++r) {
        float inv = 1.0f / lrun[r];
        int m = (b << 10) + qrow + quad * 4 + r;
        for (int d = 0; d < 4; ++d)
            out[(size_t)m * E_DIM + h * HD + d * 16 + l15] = f2bf(o[d][r] * inv);
    }
}

// ---------------- launch ----------------
extern "C" void kernel_launch(void* const* d_in, const int* in_sizes, int n_in,
                              void* d_out, int out_size, void* d_ws, size_t ws_size,
                              hipStream_t stream) {
    const float* x     = (const float*)d_in[0];
    const float* ln1_w = (const float*)d_in[1];
    const float* ln1_b = (const float*)d_in[2];
    const float* ln2_w = (const float*)d_in[3];
    const float* ln2_b = (const float*)d_in[4];
    const float* qkv_w = (const float*)d_in[5];
    const float* qkv_b = (const float*)d_in[6];
    const float* out_w = (const float*)d_in[7];
    const float* out_b = (const float*)d_in[8];
    const float* fc1_w = (const float*)d_in[9];
    const float* fc1_b = (const float*)d_in[10];
    const float* fc2_w = (const float*)d_in[11];
    const float* fc2_b = (const float*)d_in[12];

    char* ws = (char*)d_ws;
    size_t off = 0;
    auto alloc = [&](size_t bytes) { char* p = ws + off; off += bytes; return p; };
    unsigned short* wq   = (unsigned short*)alloc((size_t)3 * E_DIM * E_DIM * 2);
    unsigned short* wo   = (unsigned short*)alloc((size_t)E_DIM * E_DIM * 2);
    unsigned short* w1   = (unsigned short*)alloc((size_t)F_DIM * E_DIM * 2);
    unsigned short* w2   = (unsigned short*)alloc((size_t)E_DIM * F_DIM * 2);
    unsigned short* h1   = (unsigned short*)alloc((size_t)MROWS * E_DIM * 2);
    unsigned short* qkvb = (unsigned short*)alloc((size_t)MROWS * QKV_N * 2);
    unsigned short* attn = (unsigned short*)alloc((size_t)MROWS * E_DIM * 2);
    float*          x1   = (float*)alloc((size_t)MROWS * E_DIM * 4);
    unsigned short* h2   = (unsigned short*)alloc((size_t)MROWS * E_DIM * 2);
    unsigned short* g    = (unsigned short*)alloc((size_t)MROWS * F_DIM * 2);

    // weight conversion
    {
        int n;
        n = 3 * E_DIM * E_DIM; f2b_kernel<<<(n + 255) / 256, 256, 0, stream>>>(qkv_w, wq, n);
        n = E_DIM * E_DIM;     f2b_kernel<<<(n + 255) / 256, 256, 0, stream>>>(out_w, wo, n);
        n = F_DIM * E_DIM;     f2b_kernel<<<(n + 255) / 256, 256, 0, stream>>>(fc1_w, w1, n);
        n = E_DIM * F_DIM;     f2b_kernel<<<(n + 255) / 256, 256, 0, stream>>>(fc2_w, w2, n);
    }

    // LN1
    ln_kernel<<<MROWS, 256, 0, stream>>>(x, ln1_w, ln1_b, h1);
    // QKV gemm: [4096,3072] = h1 @ qkv_w^T -> contiguous bf16 [M,3E]
    gemm_bt<8><<<dim3(QKV_N / TN, MROWS / TM), 256, 0, stream>>>(
        h1, wq, qkv_b, nullptr, nullptr, qkvb, MROWS, QKV_N, E_DIM);
    // attention
    attn_kernel<<<dim3(SEQ / 64, BATCH * NH), 256, 0, stream>>>(qkvb, attn);
    // out proj + residual(x) -> x1 fp32
    gemm_bt<2 | 4><<<dim3(E_DIM / TN, MROWS / TM), 256, 0, stream>>>(
        attn, wo, out_b, x, x1, nullptr, MROWS, E_DIM, E_DIM);
    // LN2
    ln_kernel<<<MROWS, 256, 0, stream>>>(x1, ln2_w, ln2_b, h2);
    // FC1 + gelu -> g bf16
    gemm_bt<1 | 8><<<dim3(F_DIM / TN, MROWS / TM), 256, 0, stream>>>(
        h2, w1, fc1_b, nullptr, nullptr, g, MROWS, F_DIM, E_DIM);
    // FC2 + residual(x1) -> d_out fp32
    gemm_bt<2 | 4><<<dim3(E_DIM / TN, MROWS / TM), 256, 0, stream>>>(
        g, w2, fc2_b, x1, (float*)d_out, nullptr, MROWS, E_DIM, F_DIM);
}

// Round 3
// 391.776 us; speedup vs baseline: 1.5468x; 1.1778x over previous
//
#include <hip/hip_runtime.h>

typedef float floatx4 __attribute__((ext_vector_type(4)));
typedef short shortx8 __attribute__((ext_vector_type(8)));

#define E_DIM 1024
#define F_DIM 4096
#define BATCH 4
#define SEQ 1024
#define NH 16
#define HD 64
#define MROWS (BATCH*SEQ)   // 4096
#define QKV_N (3*E_DIM)     // 3072

typedef const __attribute__((address_space(1))) unsigned int* gas_ptr;
typedef __attribute__((address_space(3))) unsigned int* las_ptr;

__device__ __forceinline__ unsigned short f2bf(float f) {
    union { float f; unsigned u; } un; un.f = f;
    unsigned u = un.u;
    u += 0x7fffu + ((u >> 16) & 1u);   // RNE
    return (unsigned short)(u >> 16);
}

// ---------------- fp32 -> bf16 convert (weights) ----------------
__global__ void f2b_kernel(const float* __restrict__ in, unsigned short* __restrict__ out, int n) {
    int i = blockIdx.x * 256 + threadIdx.x;
    if (i < n) out[i] = f2bf(in[i]);
}

// ---------------- LayerNorm (row=1024), fp32 in, bf16 out ----------------
__global__ __launch_bounds__(256) void ln_kernel(const float* __restrict__ x,
                                                 const float* __restrict__ w,
                                                 const float* __restrict__ b,
                                                 unsigned short* __restrict__ out) {
    int row = blockIdx.x;
    const float* xr = x + (size_t)row * E_DIM;
    float v[4];
    float s = 0.f, ss = 0.f;
    for (int i = 0; i < 4; ++i) {
        v[i] = xr[threadIdx.x + i * 256];
        s += v[i]; ss += v[i] * v[i];
    }
    for (int m = 32; m; m >>= 1) { s += __shfl_xor(s, m); ss += __shfl_xor(ss, m); }
    __shared__ float red[8];
    int wave = threadIdx.x >> 6;
    if ((threadIdx.x & 63) == 0) { red[wave] = s; red[wave + 4] = ss; }
    __syncthreads();
    s = red[0] + red[1] + red[2] + red[3];
    ss = red[4] + red[5] + red[6] + red[7];
    float mu = s * (1.0f / E_DIM);
    float var = ss * (1.0f / E_DIM) - mu * mu;
    float rs = rsqrtf(var + 1e-5f);
    for (int i = 0; i < 4; ++i) {
        int c = threadIdx.x + i * 256;
        out[(size_t)row * E_DIM + c] = f2bf((v[i] - mu) * rs * w[c] + b[c]);
    }
}

// ---------------- GEMM (m97 structure, unchanged from R2) ----------------
#define TM 128
#define TN 128
#define BK 64

template<int EPI>
__global__ __launch_bounds__(256) void gemm_bt(
        const unsigned short* __restrict__ A, const unsigned short* __restrict__ Bw,
        const float* __restrict__ bias, const float* __restrict__ resid,
        float* __restrict__ Cf, unsigned short* __restrict__ Cb,
        int M, int N, int K) {
    __shared__ unsigned short sA[TM * BK];
    __shared__ unsigned short sB[TN * BK];
    int tid = threadIdx.x;
    int wave = tid >> 6, lane = tid & 63;
    int n0 = blockIdx.x * TN, m0 = blockIdx.y * TM;
    int wm = (wave & 1) * 64, wn = (wave >> 1) * 64;
    int l15 = lane & 15, quad = lane >> 4;

    int srow = wave * 32 + (lane >> 3);
    int scg  = (lane & 7) ^ (srow & 7);
    const unsigned short* Ag = A  + (size_t)(m0 + srow) * K + scg * 8;
    const unsigned short* Bg = Bw + (size_t)(n0 + srow) * K + scg * 8;

    floatx4 acc[4][4];
#pragma unroll
    for (int i = 0; i < 4; ++i)
#pragma unroll
        for (int j = 0; j < 4; ++j) acc[i][j] = (floatx4)0.f;

    for (int k0 = 0; k0 < K; k0 += BK) {
        __syncthreads();
#pragma unroll
        for (int p = 0; p < 4; ++p) {
            __builtin_amdgcn_global_load_lds((gas_ptr)(Ag + k0 + p * 8 * K),
                (las_ptr)&sA[(wave * 32 + p * 8) * BK], 16, 0, 0);
            __builtin_amdgcn_global_load_lds((gas_ptr)(Bg + k0 + p * 8 * K),
                (las_ptr)&sB[(wave * 32 + p * 8) * BK], 16, 0, 0);
        }
        __syncthreads();
#pragma unroll
        for (int kk8 = 0; kk8 < 8; kk8 += 4) {
            shortx8 af[4], bfr[4];
#pragma unroll
            for (int i = 0; i < 4; ++i) {
                int R = wm + i * 16 + l15;
                int sc = (quad + kk8) ^ (R & 7);
                af[i] = *(const shortx8*)&sA[(R * 8 + sc) * 8];
            }
#pragma unroll
            for (int j = 0; j < 4; ++j) {
                int R = wn + j * 16 + l15;
                int sc = (quad + kk8) ^ (R & 7);
                bfr[j] = *(const shortx8*)&sB[(R * 8 + sc) * 8];
            }
#pragma unroll
            for (int i = 0; i < 4; ++i)
#pragma unroll
                for (int j = 0; j < 4; ++j)
                    acc[i][j] = __builtin_amdgcn_mfma_f32_16x16x32_bf16(af[i], bfr[j], acc[i][j], 0, 0, 0);
        }
    }

#pragma unroll
    for (int i = 0; i < 4; ++i) {
        int row = m0 + wm + i * 16 + quad * 4;
#pragma unroll
        for (int j = 0; j < 4; ++j) {
            int col = n0 + wn + j * 16 + l15;
            float bs = bias[col];
#pragma unroll
            for (int r = 0; r < 4; ++r) {
                float v = acc[i][j][r] + bs;
                int rr = row + r;
                if (EPI & 1) v = 0.5f * v * (1.0f + erff(v * 0.70710678f));
                if (EPI & 2) v += resid[(size_t)rr * N + col];
                if (EPI & 4) Cf[(size_t)rr * N + col] = v;
                if (EPI & 8) Cb[(size_t)rr * N + col] = f2bf(v);
            }
        }
    }
}

// ---------------- V transpose: qkv[.,2048+h*64+d] -> vT[bh][d][t] ----------------
__global__ __launch_bounds__(256) void vtrans_kernel(const unsigned short* __restrict__ qkv,
                                                     unsigned short* __restrict__ vT) {
    __shared__ unsigned short tile[64 * 72];
    int tid = threadIdx.x;
    int bh = blockIdx.y, b = bh >> 4, h = bh & 15;
    int t0 = blockIdx.x * 64;
    const unsigned short* vsrc = qkv + (size_t)b * SEQ * QKV_N + 2 * E_DIM + h * HD;
#pragma unroll
    for (int p = 0; p < 2; ++p) {
        int idx = p * 256 + tid;
        int row = idx >> 3, col = (idx & 7) * 8;
        *(shortx8*)&tile[row * 72 + col] =
            *(const shortx8*)&vsrc[(size_t)(t0 + row) * QKV_N + col];
    }
    __syncthreads();
    int d = tid >> 2, tch = (tid & 3) * 16;
    unsigned short* dst = vT + (size_t)bh * HD * SEQ + (size_t)d * SEQ + t0 + tch;
    shortx8 a0, a1;
#pragma unroll
    for (int j = 0; j < 8; ++j) a0[j] = (short)tile[(tch + j) * 72 + d];
#pragma unroll
    for (int j = 0; j < 8; ++j) a1[j] = (short)tile[(tch + 8 + j) * 72 + d];
    *(shortx8*)&dst[0] = a0;
    *(shortx8*)&dst[8] = a1;
}

// ---------------- Flash attention: 64-key tiles, paired q-tiles, swizzled LDS ----------------
__global__ __launch_bounds__(256) void attn_kernel(
        const unsigned short* __restrict__ qkv, const unsigned short* __restrict__ vT,
        unsigned short* __restrict__ out) {
    __shared__ unsigned short kt[64 * 64];
    __shared__ unsigned short vt[64 * 64];
    __shared__ unsigned short ps[4][16 * 64];
    int tid = threadIdx.x;
    int wave = tid >> 6, lane = tid & 63, l15 = lane & 15, quad = lane >> 4;
    int bh = blockIdx.y, b = bh >> 4, h = bh & 15;
    const unsigned short* qbase = qkv + (size_t)b * SEQ * QKV_N + h * HD;
    const unsigned short* kbase = qbase + E_DIM;
    const unsigned short* vtb = vT + (size_t)bh * HD * SEQ;

    int srl = lane >> 3;                 // 0..7 row within 8-row group
    int scg = (lane & 7) ^ srl;          // swizzled global col-group

    const float scale = 0.125f * 1.44269504f;  // 1/sqrt(64) * log2(e)

    for (int pass = 0; pass < 2; ++pass) {
        int qt = (pass == 0) ? blockIdx.x : (15 - blockIdx.x);
        int q0 = qt * 64;
        int qrow = q0 + wave * 16;

        shortx8 qa0 = *(const shortx8*)&qbase[(size_t)(qrow + l15) * QKV_N + quad * 8];
        shortx8 qa1 = *(const shortx8*)&qbase[(size_t)(qrow + l15) * QKV_N + 32 + quad * 8];

        floatx4 o[4];
        for (int d = 0; d < 4; ++d) o[d] = (floatx4)0.f;
        float mrun[4], lrun[4];
        for (int r = 0; r < 4; ++r) { mrun[r] = -1e30f; lrun[r] = 0.f; }

        int ntile = qt + 1;
        for (int t = 0; t < ntile; ++t) {
            int s0 = t * 64;
            __syncthreads();
#pragma unroll
            for (int p = 0; p < 2; ++p) {
                int rbase = p * 32 + wave * 8;
                __builtin_amdgcn_global_load_lds(
                    (gas_ptr)&kbase[(size_t)(s0 + rbase + srl) * QKV_N + scg * 8],
                    (las_ptr)&kt[rbase * 64], 16, 0, 0);
                __builtin_amdgcn_global_load_lds(
                    (gas_ptr)&vtb[(size_t)(rbase + srl) * SEQ + s0 + scg * 8],
                    (las_ptr)&vt[rbase * 64], 16, 0, 0);
            }
            __syncthreads();

            // S = Q K^T for 4 col-subtiles of 16
            floatx4 sfr[4];
#pragma unroll
            for (int ct = 0; ct < 4; ++ct) {
                int R = ct * 16 + l15;
                int sc0 = quad ^ (R & 7), sc1 = (4 + quad) ^ (R & 7);
                shortx8 kb0 = *(const shortx8*)&kt[(R * 8 + sc0) * 8];
                shortx8 kb1 = *(const shortx8*)&kt[(R * 8 + sc1) * 8];
                floatx4 s4 = (floatx4)0.f;
                s4 = __builtin_amdgcn_mfma_f32_16x16x32_bf16(qa0, kb0, s4, 0, 0, 0);
                s4 = __builtin_amdgcn_mfma_f32_16x16x32_bf16(qa1, kb1, s4, 0, 0, 0);
                sfr[ct] = s4;
            }

            bool masked = (t == ntile - 1);
#pragma unroll
            for (int r = 0; r < 4; ++r) {
                int qg = qrow + quad * 4 + r;
                float sv[4];
                float mx = mrun[r];
#pragma unroll
                for (int ct = 0; ct < 4; ++ct) {
                    float v = sfr[ct][r] * scale;
                    if (masked && (s0 + ct * 16 + l15 > qg)) v = -1e30f;
                    sv[ct] = v;
                    mx = fmaxf(mx, v);
                }
                for (int mm = 8; mm; mm >>= 1) mx = fmaxf(mx, __shfl_xor(mx, mm));
                float alpha = exp2f(mrun[r] - mx);
                mrun[r] = mx;
                float sum = 0.f;
                float pv[4];
#pragma unroll
                for (int ct = 0; ct < 4; ++ct) { pv[ct] = exp2f(sv[ct] - mx); sum += pv[ct]; }
                for (int mm = 8; mm; mm >>= 1) sum += __shfl_xor(sum, mm);
                lrun[r] = lrun[r] * alpha + sum;
#pragma unroll
                for (int d = 0; d < 4; ++d) o[d][r] *= alpha;
                // write P row (swizzled, wave-private -> no barrier needed)
                int row = quad * 4 + r;
#pragma unroll
                for (int ct = 0; ct < 4; ++ct) {
                    int g = ct * 2 + (l15 >> 3);
                    int sc = g ^ (row & 7);
                    ps[wave][row * 64 + sc * 8 + (l15 & 7)] = f2bf(pv[ct]);
                }
            }
            // read P in A-layout (same-wave DS ordering guarantees visibility)
            shortx8 pa0, pa1;
            {
                int sc0 = quad ^ (l15 & 7), sc1 = (4 + quad) ^ (l15 & 7);
                pa0 = *(const shortx8*)&ps[wave][(l15 * 8 + sc0) * 8];
                pa1 = *(const shortx8*)&ps[wave][(l15 * 8 + sc1) * 8];
            }
#pragma unroll
            for (int d = 0; d < 4; ++d) {
                int R = d * 16 + l15;
                int sc0 = quad ^ (R & 7), sc1 = (4 + quad) ^ (R & 7);
                shortx8 vb0 = *(const shortx8*)&vt[(R * 8 + sc0) * 8];
                shortx8 vb1 = *(const shortx8*)&vt[(R * 8 + sc1) * 8];
                o[d] = __builtin_amdgcn_mfma_f32_16x16x32_bf16(pa0, vb0, o[d], 0, 0, 0);
                o[d] = __builtin_amdgcn_mfma_f32_16x16x32_bf16(pa1, vb1, o[d], 0, 0, 0);
            }
        }

#pragma unroll
        for (int r = 0; r < 4; ++r) {
            float inv = 1.0f / lrun[r];
            int m = (b << 10) + qrow + quad * 4 + r;
#pragma unroll
            for (int d = 0; d < 4; ++d)
                out[(size_t)m * E_DIM + h * HD + d * 16 + l15] = f2bf(o[d][r] * inv);
        }
    }
}

// ---------------- launch ----------------
extern "C" void kernel_launch(void* const* d_in, const int* in_sizes, int n_in,
                              void* d_out, int out_size, void* d_ws, size_t ws_size,
                              hipStream_t stream) {
    const float* x     = (const float*)d_in[0];
    const float* ln1_w = (const float*)d_in[1];
    const float* ln1_b = (const float*)d_in[2];
    const float* ln2_w = (const float*)d_in[3];
    const float* ln2_b = (const float*)d_in[4];
    const float* qkv_w = (const float*)d_in[5];
    const float* qkv_b = (const float*)d_in[6];
    const float* out_w = (const float*)d_in[7];
    const float* out_b = (const float*)d_in[8];
    const float* fc1_w = (const float*)d_in[9];
    const float* fc1_b = (const float*)d_in[10];
    const float* fc2_w = (const float*)d_in[11];
    const float* fc2_b = (const float*)d_in[12];

    char* ws = (char*)d_ws;
    size_t off = 0;
    auto alloc = [&](size_t bytes) { char* p = ws + off; off += bytes; return p; };
    unsigned short* wq   = (unsigned short*)alloc((size_t)3 * E_DIM * E_DIM * 2);
    unsigned short* wo   = (unsigned short*)alloc((size_t)E_DIM * E_DIM * 2);
    unsigned short* w1   = (unsigned short*)alloc((size_t)F_DIM * E_DIM * 2);
    unsigned short* w2   = (unsigned short*)alloc((size_t)E_DIM * F_DIM * 2);
    unsigned short* h1   = (unsigned short*)alloc((size_t)MROWS * E_DIM * 2);
    unsigned short* qkvb = (unsigned short*)alloc((size_t)MROWS * QKV_N * 2);
    unsigned short* vT   = (unsigned short*)alloc((size_t)BATCH * NH * HD * SEQ * 2);
    unsigned short* attn = (unsigned short*)alloc((size_t)MROWS * E_DIM * 2);
    float*          x1   = (float*)alloc((size_t)MROWS * E_DIM * 4);
    unsigned short* h2   = (unsigned short*)alloc((size_t)MROWS * E_DIM * 2);
    unsigned short* g    = (unsigned short*)alloc((size_t)MROWS * F_DIM * 2);

    {
        int n;
        n = 3 * E_DIM * E_DIM; f2b_kernel<<<(n + 255) / 256, 256, 0, stream>>>(qkv_w, wq, n);
        n = E_DIM * E_DIM;     f2b_kernel<<<(n + 255) / 256, 256, 0, stream>>>(out_w, wo, n);
        n = F_DIM * E_DIM;     f2b_kernel<<<(n + 255) / 256, 256, 0, stream>>>(fc1_w, w1, n);
        n = E_DIM * F_DIM;     f2b_kernel<<<(n + 255) / 256, 256, 0, stream>>>(fc2_w, w2, n);
    }

    ln_kernel<<<MROWS, 256, 0, stream>>>(x, ln1_w, ln1_b, h1);
    gemm_bt<8><<<dim3(QKV_N / TN, MROWS / TM), 256, 0, stream>>>(
        h1, wq, qkv_b, nullptr, nullptr, qkvb, MROWS, QKV_N, E_DIM);
    vtrans_kernel<<<dim3(SEQ / 64, BATCH * NH), 256, 0, stream>>>(qkvb, vT);
    attn_kernel<<<dim3(8, BATCH * NH), 256, 0, stream>>>(qkvb, vT, attn);
    gemm_bt<2 | 4><<<dim3(E_DIM / TN, MROWS / TM), 256, 0, stream>>>(
        attn, wo, out_b, x, x1, nullptr, MROWS, E_DIM, E_DIM);
    ln_kernel<<<MROWS, 256, 0, stream>>>(x1, ln2_w, ln2_b, h2);
    gemm_bt<1 | 8><<<dim3(F_DIM / TN, MROWS / TM), 256, 0, stream>>>(
        h2, w1, fc1_b, nullptr, nullptr, g, MROWS, F_DIM, E_DIM);
    gemm_bt<2 | 4><<<dim3(E_DIM / TN, MROWS / TM), 256, 0, stream>>>(
        g, w2, fc2_b, x1, (float*)d_out, nullptr, MROWS, E_DIM, F_DIM);
}

// Round 4
// 377.404 us; speedup vs baseline: 1.6057x; 1.0381x over previous
//
#include <hip/hip_runtime.h>

typedef float floatx4 __attribute__((ext_vector_type(4)));
typedef short shortx8 __attribute__((ext_vector_type(8)));

#define E_DIM 1024
#define F_DIM 4096
#define BATCH 4
#define SEQ 1024
#define NH 16
#define HD 64
#define MROWS (BATCH*SEQ)   // 4096
#define QKV_N (3*E_DIM)     // 3072

typedef const __attribute__((address_space(1))) unsigned int* gas_ptr;
typedef __attribute__((address_space(3))) unsigned int* las_ptr;

__device__ __forceinline__ unsigned short f2bf(float f) {
    union { float f; unsigned u; } un; un.f = f;
    unsigned u = un.u;
    u += 0x7fffu + ((u >> 16) & 1u);   // RNE
    return (unsigned short)(u >> 16);
}

// ---------------- fp32 -> bf16 convert (weights) ----------------
__global__ void f2b_kernel(const float* __restrict__ in, unsigned short* __restrict__ out, int n) {
    int i = blockIdx.x * 256 + threadIdx.x;
    if (i < n) out[i] = f2bf(in[i]);
}

// ---------------- LayerNorm (row=1024), fp32 in, bf16 out ----------------
__global__ __launch_bounds__(256) void ln_kernel(const float* __restrict__ x,
                                                 const float* __restrict__ w,
                                                 const float* __restrict__ b,
                                                 unsigned short* __restrict__ out) {
    int row = blockIdx.x;
    const float* xr = x + (size_t)row * E_DIM;
    float v[4];
    float s = 0.f, ss = 0.f;
    for (int i = 0; i < 4; ++i) {
        v[i] = xr[threadIdx.x + i * 256];
        s += v[i]; ss += v[i] * v[i];
    }
    for (int m = 32; m; m >>= 1) { s += __shfl_xor(s, m); ss += __shfl_xor(ss, m); }
    __shared__ float red[8];
    int wave = threadIdx.x >> 6;
    if ((threadIdx.x & 63) == 0) { red[wave] = s; red[wave + 4] = ss; }
    __syncthreads();
    s = red[0] + red[1] + red[2] + red[3];
    ss = red[4] + red[5] + red[6] + red[7];
    float mu = s * (1.0f / E_DIM);
    float var = ss * (1.0f / E_DIM) - mu * mu;
    float rs = rsqrtf(var + 1e-5f);
    for (int i = 0; i < 4; ++i) {
        int c = threadIdx.x + i * 256;
        out[(size_t)row * E_DIM + c] = f2bf((v[i] - mu) * rs * w[c] + b[c]);
    }
}

// ---------------- GEMM 128x128 (m97 structure) — for N>=3072 GEMMs ----------------
#define TM 128
#define TN 128
#define BK 64

template<int EPI>
__global__ __launch_bounds__(256) void gemm_bt(
        const unsigned short* __restrict__ A, const unsigned short* __restrict__ Bw,
        const float* __restrict__ bias, const float* __restrict__ resid,
        float* __restrict__ Cf, unsigned short* __restrict__ Cb,
        int M, int N, int K) {
    __shared__ unsigned short sA[TM * BK];
    __shared__ unsigned short sB[TN * BK];
    int tid = threadIdx.x;
    int wave = tid >> 6, lane = tid & 63;
    int n0 = blockIdx.x * TN, m0 = blockIdx.y * TM;
    int wm = (wave & 1) * 64, wn = (wave >> 1) * 64;
    int l15 = lane & 15, quad = lane >> 4;

    int srow = wave * 32 + (lane >> 3);
    int scg  = (lane & 7) ^ (srow & 7);
    const unsigned short* Ag = A  + (size_t)(m0 + srow) * K + scg * 8;
    const unsigned short* Bg = Bw + (size_t)(n0 + srow) * K + scg * 8;

    floatx4 acc[4][4];
#pragma unroll
    for (int i = 0; i < 4; ++i)
#pragma unroll
        for (int j = 0; j < 4; ++j) acc[i][j] = (floatx4)0.f;

    for (int k0 = 0; k0 < K; k0 += BK) {
        __syncthreads();
#pragma unroll
        for (int p = 0; p < 4; ++p) {
            __builtin_amdgcn_global_load_lds((gas_ptr)(Ag + k0 + p * 8 * K),
                (las_ptr)&sA[(wave * 32 + p * 8) * BK], 16, 0, 0);
            __builtin_amdgcn_global_load_lds((gas_ptr)(Bg + k0 + p * 8 * K),
                (las_ptr)&sB[(wave * 32 + p * 8) * BK], 16, 0, 0);
        }
        __syncthreads();
#pragma unroll
        for (int kk8 = 0; kk8 < 8; kk8 += 4) {
            shortx8 af[4], bfr[4];
#pragma unroll
            for (int i = 0; i < 4; ++i) {
                int R = wm + i * 16 + l15;
                int sc = (quad + kk8) ^ (R & 7);
                af[i] = *(const shortx8*)&sA[(R * 8 + sc) * 8];
            }
#pragma unroll
            for (int j = 0; j < 4; ++j) {
                int R = wn + j * 16 + l15;
                int sc = (quad + kk8) ^ (R & 7);
                bfr[j] = *(const shortx8*)&sB[(R * 8 + sc) * 8];
            }
#pragma unroll
            for (int i = 0; i < 4; ++i)
#pragma unroll
                for (int j = 0; j < 4; ++j)
                    acc[i][j] = __builtin_amdgcn_mfma_f32_16x16x32_bf16(af[i], bfr[j], acc[i][j], 0, 0, 0);
        }
    }

#pragma unroll
    for (int i = 0; i < 4; ++i) {
        int row = m0 + wm + i * 16 + quad * 4;
#pragma unroll
        for (int j = 0; j < 4; ++j) {
            int col = n0 + wn + j * 16 + l15;
            float bs = bias[col];
#pragma unroll
            for (int r = 0; r < 4; ++r) {
                float v = acc[i][j][r] + bs;
                int rr = row + r;
                if (EPI & 1) v = 0.5f * v * (1.0f + erff(v * 0.70710678f));
                if (EPI & 2) v += resid[(size_t)rr * N + col];
                if (EPI & 4) Cf[(size_t)rr * N + col] = v;
                if (EPI & 8) Cb[(size_t)rr * N + col] = f2bf(v);
            }
        }
    }
}

// ---------------- GEMM 128x64 — for N=1024 GEMMs (2 blocks/CU) ----------------
template<int EPI>
__global__ __launch_bounds__(256) void gemm_n64(
        const unsigned short* __restrict__ A, const unsigned short* __restrict__ Bw,
        const float* __restrict__ bias, const float* __restrict__ resid,
        float* __restrict__ Cf, unsigned short* __restrict__ Cb,
        int M, int N, int K) {
    __shared__ unsigned short sA[TM * BK];
    __shared__ unsigned short sB[64 * BK];
    int tid = threadIdx.x;
    int wave = tid >> 6, lane = tid & 63;
    int n0 = blockIdx.x * 64, m0 = blockIdx.y * TM;
    int wm = (wave & 1) * 64, wn = (wave >> 1) * 32;
    int l15 = lane & 15, quad = lane >> 4;

    int srow = wave * 32 + (lane >> 3);
    int scg  = (lane & 7) ^ (srow & 7);
    const unsigned short* Ag = A + (size_t)(m0 + srow) * K + scg * 8;
    int srB  = wave * 16 + (lane >> 3);
    int scgB = (lane & 7) ^ (srB & 7);
    const unsigned short* Bg = Bw + (size_t)(n0 + srB) * K + scgB * 8;

    floatx4 acc[4][2];
#pragma unroll
    for (int i = 0; i < 4; ++i)
#pragma unroll
        for (int j = 0; j < 2; ++j) acc[i][j] = (floatx4)0.f;

    for (int k0 = 0; k0 < K; k0 += BK) {
        __syncthreads();
#pragma unroll
        for (int p = 0; p < 4; ++p)
            __builtin_amdgcn_global_load_lds((gas_ptr)(Ag + k0 + p * 8 * K),
                (las_ptr)&sA[(wave * 32 + p * 8) * BK], 16, 0, 0);
#pragma unroll
        for (int p = 0; p < 2; ++p)
            __builtin_amdgcn_global_load_lds((gas_ptr)(Bg + k0 + p * 8 * K),
                (las_ptr)&sB[(wave * 16 + p * 8) * BK], 16, 0, 0);
        __syncthreads();
#pragma unroll
        for (int kk8 = 0; kk8 < 8; kk8 += 4) {
            shortx8 af[4], bfr[2];
#pragma unroll
            for (int i = 0; i < 4; ++i) {
                int R = wm + i * 16 + l15;
                int sc = (quad + kk8) ^ (R & 7);
                af[i] = *(const shortx8*)&sA[(R * 8 + sc) * 8];
            }
#pragma unroll
            for (int j = 0; j < 2; ++j) {
                int R = wn + j * 16 + l15;
                int sc = (quad + kk8) ^ (R & 7);
                bfr[j] = *(const shortx8*)&sB[(R * 8 + sc) * 8];
            }
#pragma unroll
            for (int i = 0; i < 4; ++i)
#pragma unroll
                for (int j = 0; j < 2; ++j)
                    acc[i][j] = __builtin_amdgcn_mfma_f32_16x16x32_bf16(af[i], bfr[j], acc[i][j], 0, 0, 0);
        }
    }

#pragma unroll
    for (int i = 0; i < 4; ++i) {
        int row = m0 + wm + i * 16 + quad * 4;
#pragma unroll
        for (int j = 0; j < 2; ++j) {
            int col = n0 + wn + j * 16 + l15;
            float bs = bias[col];
#pragma unroll
            for (int r = 0; r < 4; ++r) {
                float v = acc[i][j][r] + bs;
                int rr = row + r;
                if (EPI & 1) v = 0.5f * v * (1.0f + erff(v * 0.70710678f));
                if (EPI & 2) v += resid[(size_t)rr * N + col];
                if (EPI & 4) Cf[(size_t)rr * N + col] = v;
                if (EPI & 8) Cb[(size_t)rr * N + col] = f2bf(v);
            }
        }
    }
}

// ---------------- V transpose: qkv[.,2048+h*64+d] -> vT[bh][d][t] ----------------
__global__ __launch_bounds__(256) void vtrans_kernel(const unsigned short* __restrict__ qkv,
                                                     unsigned short* __restrict__ vT) {
    __shared__ unsigned short tile[64 * 72];
    int tid = threadIdx.x;
    int bh = blockIdx.y, b = bh >> 4, h = bh & 15;
    int t0 = blockIdx.x * 64;
    const unsigned short* vsrc = qkv + (size_t)b * SEQ * QKV_N + 2 * E_DIM + h * HD;
#pragma unroll
    for (int p = 0; p < 2; ++p) {
        int idx = p * 256 + tid;
        int row = idx >> 3, col = (idx & 7) * 8;
        *(shortx8*)&tile[row * 72 + col] =
            *(const shortx8*)&vsrc[(size_t)(t0 + row) * QKV_N + col];
    }
    __syncthreads();
    int d = tid >> 2, tch = (tid & 3) * 16;
    unsigned short* dst = vT + (size_t)bh * HD * SEQ + (size_t)d * SEQ + t0 + tch;
    shortx8 a0, a1;
#pragma unroll
    for (int j = 0; j < 8; ++j) a0[j] = (short)tile[(tch + j) * 72 + d];
#pragma unroll
    for (int j = 0; j < 8; ++j) a1[j] = (short)tile[(tch + 8 + j) * 72 + d];
    *(shortx8*)&dst[0] = a0;
    *(shortx8*)&dst[8] = a1;
}

// ---------------- Flash attention: 64-key tiles, paired q-tiles, swizzled LDS ----------------
__global__ __launch_bounds__(256) void attn_kernel(
        const unsigned short* __restrict__ qkv, const unsigned short* __restrict__ vT,
        unsigned short* __restrict__ out) {
    __shared__ unsigned short kt[64 * 64];
    __shared__ unsigned short vt[64 * 64];
    __shared__ unsigned short ps[4][16 * 64];
    int tid = threadIdx.x;
    int wave = tid >> 6, lane = tid & 63, l15 = lane & 15, quad = lane >> 4;
    int bh = blockIdx.y, b = bh >> 4, h = bh & 15;
    const unsigned short* qbase = qkv + (size_t)b * SEQ * QKV_N + h * HD;
    const unsigned short* kbase = qbase + E_DIM;
    const unsigned short* vtb = vT + (size_t)bh * HD * SEQ;

    int srl = lane >> 3;
    int scg = (lane & 7) ^ srl;

    const float scale = 0.125f * 1.44269504f;

    for (int pass = 0; pass < 2; ++pass) {
        int qt = (pass == 0) ? blockIdx.x : (15 - blockIdx.x);
        int q0 = qt * 64;
        int qrow = q0 + wave * 16;

        shortx8 qa0 = *(const shortx8*)&qbase[(size_t)(qrow + l15) * QKV_N + quad * 8];
        shortx8 qa1 = *(const shortx8*)&qbase[(size_t)(qrow + l15) * QKV_N + 32 + quad * 8];

        floatx4 o[4];
        for (int d = 0; d < 4; ++d) o[d] = (floatx4)0.f;
        float mrun[4], lrun[4];
        for (int r = 0; r < 4; ++r) { mrun[r] = -1e30f; lrun[r] = 0.f; }

        int ntile = qt + 1;
        for (int t = 0; t < ntile; ++t) {
            int s0 = t * 64;
            __syncthreads();
#pragma unroll
            for (int p = 0; p < 2; ++p) {
                int rbase = p * 32 + wave * 8;
                __builtin_amdgcn_global_load_lds(
                    (gas_ptr)&kbase[(size_t)(s0 + rbase + srl) * QKV_N + scg * 8],
                    (las_ptr)&kt[rbase * 64], 16, 0, 0);
                __builtin_amdgcn_global_load_lds(
                    (gas_ptr)&vtb[(size_t)(rbase + srl) * SEQ + s0 + scg * 8],
                    (las_ptr)&vt[rbase * 64], 16, 0, 0);
            }
            __syncthreads();

            floatx4 sfr[4];
#pragma unroll
            for (int ct = 0; ct < 4; ++ct) {
                int R = ct * 16 + l15;
                int sc0 = quad ^ (R & 7), sc1 = (4 + quad) ^ (R & 7);
                shortx8 kb0 = *(const shortx8*)&kt[(R * 8 + sc0) * 8];
                shortx8 kb1 = *(const shortx8*)&kt[(R * 8 + sc1) * 8];
                floatx4 s4 = (floatx4)0.f;
                s4 = __builtin_amdgcn_mfma_f32_16x16x32_bf16(qa0, kb0, s4, 0, 0, 0);
                s4 = __builtin_amdgcn_mfma_f32_16x16x32_bf16(qa1, kb1, s4, 0, 0, 0);
                sfr[ct] = s4;
            }

            bool masked = (t == ntile - 1);
#pragma unroll
            for (int r = 0; r < 4; ++r) {
                int qg = qrow + quad * 4 + r;
                float sv[4];
                float mx = mrun[r];
#pragma unroll
                for (int ct = 0; ct < 4; ++ct) {
                    float v = sfr[ct][r] * scale;
                    if (masked && (s0 + ct * 16 + l15 > qg)) v = -1e30f;
                    sv[ct] = v;
                    mx = fmaxf(mx, v);
                }
                for (int mm = 8; mm; mm >>= 1) mx = fmaxf(mx, __shfl_xor(mx, mm));
                float alpha = exp2f(mrun[r] - mx);
                mrun[r] = mx;
                float sum = 0.f;
                float pv[4];
#pragma unroll
                for (int ct = 0; ct < 4; ++ct) { pv[ct] = exp2f(sv[ct] - mx); sum += pv[ct]; }
                for (int mm = 8; mm; mm >>= 1) sum += __shfl_xor(sum, mm);
                lrun[r] = lrun[r] * alpha + sum;
#pragma unroll
                for (int d = 0; d < 4; ++d) o[d][r] *= alpha;
                int row = quad * 4 + r;
#pragma unroll
                for (int ct = 0; ct < 4; ++ct) {
                    int g = ct * 2 + (l15 >> 3);
                    int sc = g ^ (row & 7);
                    ps[wave][row * 64 + sc * 8 + (l15 & 7)] = f2bf(pv[ct]);
                }
            }
            shortx8 pa0, pa1;
            {
                int sc0 = quad ^ (l15 & 7), sc1 = (4 + quad) ^ (l15 & 7);
                pa0 = *(const shortx8*)&ps[wave][(l15 * 8 + sc0) * 8];
                pa1 = *(const shortx8*)&ps[wave][(l15 * 8 + sc1) * 8];
            }
#pragma unroll
            for (int d = 0; d < 4; ++d) {
                int R = d * 16 + l15;
                int sc0 = quad ^ (R & 7), sc1 = (4 + quad) ^ (R & 7);
                shortx8 vb0 = *(const shortx8*)&vt[(R * 8 + sc0) * 8];
                shortx8 vb1 = *(const shortx8*)&vt[(R * 8 + sc1) * 8];
                o[d] = __builtin_amdgcn_mfma_f32_16x16x32_bf16(pa0, vb0, o[d], 0, 0, 0);
                o[d] = __builtin_amdgcn_mfma_f32_16x16x32_bf16(pa1, vb1, o[d], 0, 0, 0);
            }
        }

#pragma unroll
        for (int r = 0; r < 4; ++r) {
            float inv = 1.0f / lrun[r];
            int m = (b << 10) + qrow + quad * 4 + r;
#pragma unroll
            for (int d = 0; d < 4; ++d)
                out[(size_t)m * E_DIM + h * HD + d * 16 + l15] = f2bf(o[d][r] * inv);
        }
    }
}

// ---------------- launch ----------------
extern "C" void kernel_launch(void* const* d_in, const int* in_sizes, int n_in,
                              void* d_out, int out_size, void* d_ws, size_t ws_size,
                              hipStream_t stream) {
    const float* x     = (const float*)d_in[0];
    const float* ln1_w = (const float*)d_in[1];
    const float* ln1_b = (const float*)d_in[2];
    const float* ln2_w = (const float*)d_in[3];
    const float* ln2_b = (const float*)d_in[4];
    const float* qkv_w = (const float*)d_in[5];
    const float* qkv_b = (const float*)d_in[6];
    const float* out_w = (const float*)d_in[7];
    const float* out_b = (const float*)d_in[8];
    const float* fc1_w = (const float*)d_in[9];
    const float* fc1_b = (const float*)d_in[10];
    const float* fc2_w = (const float*)d_in[11];
    const float* fc2_b = (const float*)d_in[12];

    char* ws = (char*)d_ws;
    size_t off = 0;
    auto alloc = [&](size_t bytes) { char* p = ws + off; off += bytes; return p; };
    unsigned short* wq   = (unsigned short*)alloc((size_t)3 * E_DIM * E_DIM * 2);
    unsigned short* wo   = (unsigned short*)alloc((size_t)E_DIM * E_DIM * 2);
    unsigned short* w1   = (unsigned short*)alloc((size_t)F_DIM * E_DIM * 2);
    unsigned short* w2   = (unsigned short*)alloc((size_t)E_DIM * F_DIM * 2);
    unsigned short* h1   = (unsigned short*)alloc((size_t)MROWS * E_DIM * 2);
    unsigned short* qkvb = (unsigned short*)alloc((size_t)MROWS * QKV_N * 2);
    unsigned short* vT   = (unsigned short*)alloc((size_t)BATCH * NH * HD * SEQ * 2);
    unsigned short* attn = (unsigned short*)alloc((size_t)MROWS * E_DIM * 2);
    float*          x1   = (float*)alloc((size_t)MROWS * E_DIM * 4);
    unsigned short* h2   = (unsigned short*)alloc((size_t)MROWS * E_DIM * 2);
    unsigned short* g    = (unsigned short*)alloc((size_t)MROWS * F_DIM * 2);

    {
        int n;
        n = 3 * E_DIM * E_DIM; f2b_kernel<<<(n + 255) / 256, 256, 0, stream>>>(qkv_w, wq, n);
        n = E_DIM * E_DIM;     f2b_kernel<<<(n + 255) / 256, 256, 0, stream>>>(out_w, wo, n);
        n = F_DIM * E_DIM;     f2b_kernel<<<(n + 255) / 256, 256, 0, stream>>>(fc1_w, w1, n);
        n = E_DIM * F_DIM;     f2b_kernel<<<(n + 255) / 256, 256, 0, stream>>>(fc2_w, w2, n);
    }

    ln_kernel<<<MROWS, 256, 0, stream>>>(x, ln1_w, ln1_b, h1);
    gemm_bt<8><<<dim3(QKV_N / TN, MROWS / TM), 256, 0, stream>>>(
        h1, wq, qkv_b, nullptr, nullptr, qkvb, MROWS, QKV_N, E_DIM);
    vtrans_kernel<<<dim3(SEQ / 64, BATCH * NH), 256, 0, stream>>>(qkvb, vT);
    attn_kernel<<<dim3(8, BATCH * NH), 256, 0, stream>>>(qkvb, vT, attn);
    // out proj + residual(x) -> x1 fp32   (N=1024: 128x64 tiles, 512 blocks)
    gemm_n64<2 | 4><<<dim3(E_DIM / 64, MROWS / TM), 256, 0, stream>>>(
        attn, wo, out_b, x, x1, nullptr, MROWS, E_DIM, E_DIM);
    ln_kernel<<<MROWS, 256, 0, stream>>>(x1, ln2_w, ln2_b, h2);
    gemm_bt<1 | 8><<<dim3(F_DIM / TN, MROWS / TM), 256, 0, stream>>>(
        h2, w1, fc1_b, nullptr, nullptr, g, MROWS, F_DIM, E_DIM);
    // FC2 + residual(x1) -> d_out fp32   (N=1024: 128x64 tiles, 512 blocks)
    gemm_n64<2 | 4><<<dim3(E_DIM / 64, MROWS / TM), 256, 0, stream>>>(
        g, w2, fc2_b, x1, (float*)d_out, nullptr, MROWS, E_DIM, F_DIM);
}